// Round 7
// baseline (18.299 us; speedup 1.0000x reference)
//
#include <hip/hip_runtime.h>

// FeatureViewEncoder: per-feature Conv1d(1,H,3) + mask + max-over-time.
// out[b,f,h] = max_{l: mask[b,l]!=0} ( sum_k x[b,l+k,f]*w[f,h,k] + bias[f,h] ), else -1e9.
//
// R7: LDS-instruction-minimized. Wave = 4f x 8h x 2l (NF*NL=8), HPT=16.
// Per-CU main-loop ds_read_b128 halved vs R6 (the measured wall: ~12cyc/instr
// on the per-CU LDS pipe). b128 reads are exactly conflict-free:
// banks = 8*f_sub + 4*l_lane + 0..3 cover all 32 banks once (WSTR%32==8).

#define NEG_INF_F (-1e9f)

typedef float v2f __attribute__((ext_vector_type(2)));

constexpr int B_ = 128;
constexpr int V_ = 200;
constexpr int F_ = 64;
constexpr int H_ = 128;
constexpr int L_ = V_ - 3 + 1;   // 198

constexpr int NTHR = 256;
constexpr int FG   = 16;                   // features per block (4 waves x 4 f)
constexpr int NFW  = 4;                    // f-rows per wave
constexpr int HPT  = 16;                   // h-outputs per thread (8 packed pairs)
constexpr int MAXW = (L_ + 7) & ~7;        // 200 windows max, mult of 8
constexpr int WSTR = 4 * MAXW + 8;         // 808 floats: 808%32==8 -> f-rows 8 banks apart

__global__ __launch_bounds__(NTHR)
void fve_kernel(const float* __restrict__ x,     // [B,V,F]
                const int*   __restrict__ mask,  // [B,1,L]
                const float* __restrict__ w,     // [F,H,K]
                const float* __restrict__ bias,  // [F,H]
                float* __restrict__ out)         // [B,F,H]
{
    __shared__ __align__(16) float xc[FG][WSTR];  // compacted windows: xc[f][4j+k]
    __shared__ int vlist[L_];
    __shared__ int vcnt;

    const int b  = blockIdx.x >> 2;        // grid = B * (F/FG) = 512
    const int f0 = (blockIdx.x & 3) * FG;
    const int t  = threadIdx.x;

    if (t == 0) vcnt = 0;
    __syncthreads();

    // Phase A: compact valid time-steps (order irrelevant for max).
    if (t < L_ && mask[b * L_ + t] != 0) {
        const int p = atomicAdd(&vcnt, 1);
        vlist[p] = t;
    }
    __syncthreads();

    const int n    = vcnt;
    const int npad = (n + 7) & ~7;   // mult of 8 (dup window 0; max is idempotent)

    // Phase B: build stride-4 windows straight from global:
    //   xc[4q+c][4j+k] = x[b, l_j+k, f0+4q+c], k=0..2 (slot 3 = don't-care pad).
    // item = j*16 + k*4 + q ; k==3 lanes idle (25% of this short phase only).
    for (int item = t; item < npad * 16; item += NTHR) {
        const int j = item >> 4;
        const int k = (item >> 2) & 3;
        const int q = item & 3;
        if (k == 3) continue;
        const int l = (j < n) ? vlist[j] : vlist[0];
        const float4 g = *reinterpret_cast<const float4*>(
            x + ((size_t)b * V_ + l + k) * F_ + f0 + q * 4);
        const int col = 4 * j + k;
        xc[4 * q + 0][col] = g.x;
        xc[4 * q + 1][col] = g.y;
        xc[4 * q + 2][col] = g.z;
        xc[4 * q + 3][col] = g.w;
    }
    __syncthreads();

    // Thread map: wave = 4 f-rows x 8 h-lanes x 2 l-lanes.
    const int wave    = t >> 6;
    const int lane    = t & 63;
    const int f_sub   = lane >> 4;          // 0..3
    const int h_lane  = (lane >> 1) & 7;    // 0..7
    const int l_lane  = lane & 1;
    const int f_local = wave * NFW + f_sub; // 0..15
    const int f       = f0 + f_local;
    const int h0      = h_lane * HPT;       // 0,16,...,112

    // Weights for h0..h0+15 (48 contiguous floats, layout [h][k]) + 16 bias.
    const float* wp = w + ((size_t)f * H_ + h0) * 3;
    float wt[48];
#pragma unroll
    for (int j = 0; j < 12; ++j)
        *reinterpret_cast<float4*>(&wt[j * 4]) =
            *reinterpret_cast<const float4*>(wp + j * 4);

    float bsc[16];
#pragma unroll
    for (int j = 0; j < 4; ++j)
        *reinterpret_cast<float4*>(&bsc[j * 4]) =
            *reinterpret_cast<const float4*>(bias + (size_t)f * H_ + h0 + j * 4);

    v2f wp0[8], wp1[8], wp2[8], bpk[8], mpk[8];
#pragma unroll
    for (int p = 0; p < 8; ++p) {
        wp0[p] = (v2f){wt[6 * p + 0], wt[6 * p + 3]};
        wp1[p] = (v2f){wt[6 * p + 1], wt[6 * p + 4]};
        wp2[p] = (v2f){wt[6 * p + 2], wt[6 * p + 5]};
        bpk[p] = (v2f){bsc[2 * p], bsc[2 * p + 1]};
        mpk[p] = (v2f){NEG_INF_F, NEG_INF_F};
    }

    const float4* xq = reinterpret_cast<const float4*>(&xc[f_local][0]);

#define PROCQ(Q)                                                              \
    do {                                                                      \
        const v2f X0 = (v2f){(Q).x, (Q).x};                                   \
        const v2f X1 = (v2f){(Q).y, (Q).y};                                   \
        const v2f X2 = (v2f){(Q).z, (Q).z};                                   \
        _Pragma("unroll")                                                     \
        for (int p = 0; p < 8; ++p) {                                         \
            const v2f c = __builtin_elementwise_fma(X0, wp0[p],               \
                          __builtin_elementwise_fma(X1, wp1[p],               \
                          __builtin_elementwise_fma(X2, wp2[p], bpk[p])));    \
            mpk[p] = __builtin_elementwise_max(mpk[p], c);                    \
        }                                                                     \
    } while (0)

    // Inner loop: 1 conflict-free ds_read_b128 per window; lane handles
    // windows l_lane, l_lane+2, ... npad%8==0 -> clean 4x batch per step.
    for (int u = 0; u < npad; u += 8) {
        const int i0 = u + l_lane;
        const float4 q0 = xq[i0];
        const float4 q1 = xq[i0 + 2];
        const float4 q2 = xq[i0 + 4];
        const float4 q3 = xq[i0 + 6];
        PROCQ(q0);
        PROCQ(q1);
        PROCQ(q2);
        PROCQ(q3);
    }
#undef PROCQ

    // Reduce across the l_lane pair (lanes t, t^1 hold same (f,h0)).
#pragma unroll
    for (int p = 0; p < 8; ++p) {
        const float a = __shfl_xor(mpk[p].x, 1, 64);
        const float c = __shfl_xor(mpk[p].y, 1, 64);
        mpk[p].x = fmaxf(mpk[p].x, a);
        mpk[p].y = fmaxf(mpk[p].y, c);
    }

    // l_lane 0 writes h0..h0+7, l_lane 1 writes h0+8..h0+15 (2 float4 each).
    float* op = out + ((size_t)b * F_ + f) * H_ + h0 + l_lane * 8;
    const int pb = l_lane * 4;
    *reinterpret_cast<float4*>(op) =
        make_float4(mpk[pb].x, mpk[pb].y, mpk[pb + 1].x, mpk[pb + 1].y);
    *reinterpret_cast<float4*>(op + 4) =
        make_float4(mpk[pb + 2].x, mpk[pb + 2].y, mpk[pb + 3].x, mpk[pb + 3].y);
}

extern "C" void kernel_launch(void* const* d_in, const int* in_sizes, int n_in,
                              void* d_out, int out_size, void* d_ws, size_t ws_size,
                              hipStream_t stream) {
    const float* x    = (const float*)d_in[0];  // input_visit
    const int*   mask = (const int*)d_in[1];    // visit_mask
    const float* w    = (const float*)d_in[2];  // conv_w
    const float* bias = (const float*)d_in[3];  // conv_b
    float* out = (float*)d_out;

    const int grid = B_ * (F_ / FG);  // 512
    fve_kernel<<<grid, NTHR, 0, stream>>>(x, mask, w, bias, out);
}